// Round 1
// baseline (187.124 us; speedup 1.0000x reference)
//
#include <hip/hip_runtime.h>

// out[b, n, k, :] = features[b, topk_indices[b, n, k], :]
// B=32, N=4096, K=20, F=64, fp32.
// Write-BW-bound: 671 MB out, 33.5 MB features (L2-resident), 10.5 MB idx.

constexpr int B = 32, N = 4096, K = 20, F = 64;
constexpr unsigned TOTAL_ROWS = (unsigned)B * N * K;          // 2,621,440
constexpr unsigned VEC_PER_ROW = F / 4;                       // 16 float4 per row
constexpr unsigned TOTAL_VEC = TOTAL_ROWS * VEC_PER_ROW;      // 41,943,040 (< 2^31)
constexpr unsigned NK = (unsigned)N * K;                      // 81,920

__global__ __launch_bounds__(256) void gather_rows_kernel(
    const int* __restrict__ idx,      // [B, N, K]
    const float* __restrict__ feat,   // [B, N, F]
    float* __restrict__ out)          // [B, N, K, F]
{
    unsigned i = blockIdx.x * blockDim.x + threadIdx.x;
    const unsigned stride = gridDim.x * blockDim.x;
    const float4* __restrict__ featv = reinterpret_cast<const float4*>(feat);
    float4* __restrict__ outv = reinterpret_cast<float4*>(out);

    for (; i < TOTAL_VEC; i += stride) {
        unsigned row = i >> 4;          // which output row [0, B*N*K)
        unsigned v   = i & 15u;         // float4 slot within the 64-float row
        unsigned b   = row / NK;        // batch (compiler -> magic multiply)
        int id       = idx[row];        // 16 lanes share this dword (L1 broadcast)
        // features[b, id, :] as float4s
        unsigned src = (b * (unsigned)N + (unsigned)id) * VEC_PER_ROW + v;
        outv[i] = featv[src];
    }
}

extern "C" void kernel_launch(void* const* d_in, const int* in_sizes, int n_in,
                              void* d_out, int out_size, void* d_ws, size_t ws_size,
                              hipStream_t stream) {
    const int*   idx  = (const int*)d_in[0];    // topk_indices [B,N,K] int32
    const float* feat = (const float*)d_in[1];  // features [B,N,F] fp32
    float*       out  = (float*)d_out;          // [B,N,K,F] fp32

    const int block = 256;
    const int grid = 2048;  // grid-stride; ~80 iters/thread
    gather_rows_kernel<<<grid, block, 0, stream>>>(idx, feat, out);
}